// Round 10
// baseline (283.911 us; speedup 1.0000x reference)
//
#include <hip/hip_runtime.h>

typedef __attribute__((ext_vector_type(8))) short short8;
typedef __attribute__((ext_vector_type(8))) _Float16 half8;
typedef __attribute__((ext_vector_type(2))) __fp16 fp16x2;
typedef __attribute__((ext_vector_type(2))) unsigned int uint2v;
typedef __attribute__((ext_vector_type(16))) float f32x16;
typedef __attribute__((ext_vector_type(4))) float f32x4;
typedef __attribute__((ext_vector_type(4))) unsigned short u16x4;
typedef __attribute__((ext_vector_type(8))) unsigned short u16x8;
typedef unsigned int u32;
typedef unsigned short u16;

#define B_ 8
#define H_ 8
#define N_ 2048
#define D_ 64
#define PSTR 72   // LDS row stride (shorts)
#define TSTR 66   // conv transpose LDS stride (floats)
#define ELEMS 8388608             // B*H*N*D
#define WS_NEED ((48ull << 20) + 4096ull)

static __device__ inline u16 bfhi(float x) {
  u32 u = __float_as_uint(x);
  return (u16)((u + 0x7FFFu + ((u >> 16) & 1u)) >> 16);
}
static __device__ inline float bf2f(u16 h) { return __uint_as_float((u32)h << 16); }
static __device__ inline u16 h2u(_Float16 h) { union { _Float16 f; u16 u; } c; c.f = h; return c.u; }

static __device__ __forceinline__ u32 pkrtz_u32(float a, float b) {
  union { fp16x2 h; u32 u; } c;
  c.h = __builtin_amdgcn_cvt_pkrtz(a, b);
  return c.u;
}

// softmax numerator p = exp(10*tanh(s/8) - 10) = exp2(-28.85/(1+exp2(s*.3607)))
template <bool TAIL>
static __device__ __forceinline__ float pnum(float s, int key, int rem) {
  float t = __builtin_amdgcn_exp2f(s * 0.36067376022224087f);
  float e = __builtin_amdgcn_rcpf(1.f + t) * -28.853900817779268f;
  if (TAIL) e = (key < rem) ? e : -16384.f;
  return __builtin_amdgcn_exp2f(e);
}

// quads: regs 4q..4q+3 cover keys 8q+4hl..4hl+3. A-frag needs k=32h+16g+8hl+j.
// hl=0: own even-quad then partner even-quad; hl=1: partner odd-quad then own
// odd-quad -> one permlane32_swap pair per 8-key group.
static __device__ __forceinline__ half8 pack_frag(
    float qa, float qb, float qc, float qd,
    float qe, float qf, float qg, float qh) {
  u32 E0 = pkrtz_u32(qa, qb);
  u32 E1 = pkrtz_u32(qc, qd);
  u32 O0 = pkrtz_u32(qe, qf);
  u32 O1 = pkrtz_u32(qg, qh);
  uint2v w0 = __builtin_amdgcn_permlane32_swap(E0, O0, false, false);
  uint2v w1 = __builtin_amdgcn_permlane32_swap(E1, O1, false, false);
  union { u32 u[4]; half8 v; } c;
  c.u[0] = w0[0]; c.u[1] = w1[0]; c.u[2] = w0[1]; c.u[3] = w1[1];
  return c.v;
}

struct FragSum { half8 f; float s; };   // by-value, no address-taken arrays

// 8 consecutive S elements (rbase..rbase+7) -> one PV A-frag + partial row-sum.
template <bool TAIL>
static __device__ __forceinline__ FragSum pack8(
    f32x16 S, int rbase, int koff, int rem) {
#define KEYI(i) ((((rbase) + (i)) & 3) + 8 * (((rbase) + (i)) >> 2) + (koff))
  float pA = pnum<TAIL>(S[rbase + 0], KEYI(0), rem);
  float pB = pnum<TAIL>(S[rbase + 1], KEYI(1), rem);
  float pC = pnum<TAIL>(S[rbase + 2], KEYI(2), rem);
  float pD = pnum<TAIL>(S[rbase + 3], KEYI(3), rem);
  float pE = pnum<TAIL>(S[rbase + 4], KEYI(4), rem);
  float pF = pnum<TAIL>(S[rbase + 5], KEYI(5), rem);
  float pG = pnum<TAIL>(S[rbase + 6], KEYI(6), rem);
  float pH = pnum<TAIL>(S[rbase + 7], KEYI(7), rem);
#undef KEYI
  FragSum o;
  o.f = pack_frag(pA, pB, pC, pD, pE, pF, pG, pH);
  o.s = ((pA + pB) + (pC + pD)) + ((pE + pF) + (pG + pH));
  return o;
}

// ---- fused prepass: in-block mask scan + compacted gather + convert -------
// K -> f16 (hi,lo) dense rows; V -> [bh][d][key] f16. cnt[b] written by h==0,kt==0.
__global__ __launch_bounds__(256) void conv_kv3(
    const float* __restrict__ K, const float* __restrict__ V,
    const int* __restrict__ maskg,
    u16* __restrict__ Khi, u16* __restrict__ Klo, u16* __restrict__ VThi,
    int* __restrict__ cnt) {
  const int kt = blockIdx.x, bh = blockIdx.y, b = bh >> 3, tid = threadIdx.x;
  const int lane = tid & 63, wv = tid >> 6;
  __shared__ float sT[64 * TSTR];
  __shared__ int sIdx[64];
  __shared__ int wsum[4];
  // redundant per-block scan of this batch's 2048-key mask (cheap, kills a launch)
  const int n0 = tid * 8;
  u32 bits = 0; int c = 0;
#pragma unroll
  for (int i = 0; i < 8; ++i)
    if (maskg[b * N_ + n0 + i] == 0) { bits |= (1u << i); ++c; }  // mask==0 kept
  int inc = c;
#pragma unroll
  for (int off = 1; off < 64; off <<= 1) {
    int v = __shfl_up(inc, off);
    if (lane >= off) inc += v;
  }
  if (lane == 63) wsum[wv] = inc;
  if (tid < 64) sIdx[tid] = -1;
  __syncthreads();
  const int cntb = wsum[0] + wsum[1] + wsum[2] + wsum[3];
  int o = inc - c;
#pragma unroll
  for (int k2 = 0; k2 < 4; ++k2) if (k2 < wv) o += wsum[k2];
  const int k0 = kt * 64;
#pragma unroll
  for (int i = 0; i < 8; ++i)
    if (bits & (1u << i)) {
      if (o >= k0 && o < k0 + 64) sIdx[o - k0] = n0 + i;
      ++o;
    }
  if (kt == 0 && (bh & 7) == 0 && tid == 0) cnt[b] = cntb;
  __syncthreads();
  const int nt = (cntb + 63) >> 6;
  if (kt >= nt) return;

  const size_t ibh = (size_t)bh * N_ * D_;
  const size_t okb = ibh + (size_t)kt * 64 * D_;   // compacted K row base
#pragma unroll
  for (int cc = 0; cc < 2; ++cc) {
    const int ci = tid + cc * 256, row = ci >> 3, seg = ci & 7;
    const int n = sIdx[row];
    f32x4 a, b2, va, vb2;
    if (n >= 0) {
      const float* kp = K + ibh + (size_t)n * D_ + seg * 8;
      a  = __builtin_nontemporal_load((const f32x4*)kp);
      b2 = __builtin_nontemporal_load((const f32x4*)(kp + 4));
      const float* vp = V + ibh + (size_t)n * D_ + seg * 8;
      va  = __builtin_nontemporal_load((const f32x4*)vp);
      vb2 = __builtin_nontemporal_load((const f32x4*)(vp + 4));
    } else {
#pragma unroll
      for (int j = 0; j < 4; ++j) { a[j] = 0.f; b2[j] = 0.f; va[j] = 0.f; vb2[j] = 0.f; }
    }
    u16x8 h, l;
#pragma unroll
    for (int j = 0; j < 4; ++j) {
      _Float16 h0 = (_Float16)a[j];
      h[j] = h2u(h0); l[j] = h2u((_Float16)(a[j] - (float)h0));
      _Float16 h1 = (_Float16)b2[j];
      h[j + 4] = h2u(h1); l[j + 4] = h2u((_Float16)(b2[j] - (float)h1));
    }
    *(u16x8*)&Khi[okb + row * D_ + seg * 8] = h;
    *(u16x8*)&Klo[okb + row * D_ + seg * 8] = l;
    *(f32x4*)&sT[row * TSTR + seg * 8]     = va;
    *(f32x4*)&sT[row * TSTR + seg * 8 + 4] = vb2;
  }
  __syncthreads();
  // 4x4 in-register transpose: 4 vector row-reads, 4 coalesced 8B col-writes.
  const int key0 = (tid & 15) * 4, d0 = (tid >> 4) * 4;
  f32x4 r0 = *(const f32x4*)&sT[(key0 + 0) * TSTR + d0];
  f32x4 r1 = *(const f32x4*)&sT[(key0 + 1) * TSTR + d0];
  f32x4 r2 = *(const f32x4*)&sT[(key0 + 2) * TSTR + d0];
  f32x4 r3 = *(const f32x4*)&sT[(key0 + 3) * TSTR + d0];
  const size_t ob = (size_t)bh * D_ * N_ + (size_t)kt * 64 + key0;
#pragma unroll
  for (int j = 0; j < 4; ++j) {
    u16x4 ov;
    ov[0] = h2u((_Float16)r0[j]); ov[1] = h2u((_Float16)r1[j]);
    ov[2] = h2u((_Float16)r2[j]); ov[3] = h2u((_Float16)r3[j]);
    *(u16x4*)&VThi[ob + (size_t)(d0 + j) * N_] = ov;
  }
}

// -- main kernel: swapped QK^T, in-reg softmax, reg-prefetch, XCD-homed bh ---
__global__ __launch_bounds__(256, 4) void attn_mfma9(
    const float* __restrict__ Qg,
    const u16* __restrict__ Khi, const u16* __restrict__ Klo,
    const u16* __restrict__ VThi,
    const int* __restrict__ cnt, float* __restrict__ Og)
{
  // XCD-homing swizzle: linear blk -> XCD blk&7 (round-robin dispatch). All
  // 16 qtile-blocks of a bh live on ONE XCD so K/V is fetched once into its
  // L2 (8 bh * 384 KB = 3 MB < 4 MB). Q uses non-temporal LOADS so its
  // stream doesn't evict the shared K/V set. O uses NORMAL stores --
  // nontemporal scalar stores bypass L2 write-combining (R9: 601 MB writes).
  const int blk = blockIdx.x;
  const int xcd = blk & 7, slot = blk >> 3;
  const int bh = ((slot >> 4) << 3) | xcd;   // 8 bh per XCD
  const int qtile = slot & 15;               // 0..15 (128 q-rows each)
  const int b = bh >> 3;
  const int tid = threadIdx.x, w = tid >> 6, lane = tid & 63;
  const int l32 = lane & 31, hl = lane >> 5;
  const int cntb = cnt[b];
  const int nt = (cntb + 63) >> 6;
  const bool partial = (cntb & 63) != 0;

  __shared__ short sKh[64 * PSTR], sKl[64 * PSTR];
  __shared__ short sVh[64 * PSTR];

  // ---- Q fragments (f16 hi/lo): lane holds Q[q=w*32+l32][k=s*16+hl*8+j] ----
  half8 qfh[4], qfl[4];
  {
    const float* qp = Qg + ((size_t)bh * N_ + qtile * 128 + w * 32 + l32) * D_ + hl * 8;
#pragma unroll
    for (int s = 0; s < 4; ++s) {
      f32x4 a = __builtin_nontemporal_load((const f32x4*)(qp + s * 16));
      f32x4 c = __builtin_nontemporal_load((const f32x4*)(qp + s * 16 + 4));
#pragma unroll
      for (int j = 0; j < 4; ++j) {
        _Float16 h0 = (_Float16)a[j];
        qfh[s][j] = h0; qfl[s][j] = (_Float16)(a[j] - (float)h0);
        _Float16 h1 = (_Float16)c[j];
        qfh[s][j + 4] = h1; qfl[s][j + 4] = (_Float16)(c[j] - (float)h1);
      }
    }
  }

  f32x16 accO0, accO1;
#pragma unroll
  for (int i = 0; i < 16; ++i) { accO0[i] = 0.f; accO1[i] = 0.f; }
  float dsum = 0.f;

  const size_t kvb = (size_t)bh * N_ * D_;

  // ---- affine prefetch pointers (no per-tile 64-bit recompute) ----
  const int prow = tid >> 3, pseg = tid & 7;
  const u16* pKh = Khi + kvb + (size_t)prow * D_ + pseg * 8;
  const u16* pKl = Klo + kvb + (size_t)prow * D_ + pseg * 8;
  const u16* pV  = VThi + kvb + (size_t)prow * N_ + pseg * 8;

  // ---- prologue: prefetch tile 0 into registers ----
  short8 rKh[2], rKl[2], rVh[2];
  rKh[0] = *(const short8*)pKh; rKh[1] = *(const short8*)(pKh + 32 * D_);
  rKl[0] = *(const short8*)pKl; rKl[1] = *(const short8*)(pKl + 32 * D_);
  rVh[0] = *(const short8*)pV;  rVh[1] = *(const short8*)(pV + 32 * N_);
  pKh += 64 * D_; pKl += 64 * D_; pV += 64;

  for (int kt = 0; kt < nt; ++kt) {
    __syncthreads();   // (A) prev tile's sK/sV reads complete

    // ---- staging: write prefetched regs to LDS (b128 ds_writes) ----
    {
      const int lofs = prow * PSTR + pseg * 8;
      *(short8*)&sKh[lofs] = rKh[0]; *(short8*)&sKh[lofs + 32 * PSTR] = rKh[1];
      *(short8*)&sKl[lofs] = rKl[0]; *(short8*)&sKl[lofs + 32 * PSTR] = rKl[1];
      *(short8*)&sVh[lofs] = rVh[0]; *(short8*)&sVh[lofs + 32 * PSTR] = rVh[1];
    }
    __syncthreads();   // (B)

    // ---- S^T = K Q^T: C col = q-row (l32), C rows = keys (in-register) ----
    f32x16 S0, S1;
#pragma unroll
    for (int i = 0; i < 16; ++i) { S0[i] = 0.f; S1[i] = 0.f; }
    __builtin_amdgcn_s_setprio(1);
#pragma unroll
    for (int s = 0; s < 4; ++s) {
      const int o0 = l32 * PSTR + s * 16 + hl * 8;
      half8 kfh = *(const half8*)&sKh[o0];
      half8 kfl = *(const half8*)&sKl[o0];
      S0 = __builtin_amdgcn_mfma_f32_32x32x16_f16(kfh, qfh[s], S0, 0, 0, 0);
      S0 = __builtin_amdgcn_mfma_f32_32x32x16_f16(kfl, qfh[s], S0, 0, 0, 0);
      S0 = __builtin_amdgcn_mfma_f32_32x32x16_f16(kfh, qfl[s], S0, 0, 0, 0);
      const int o1 = (32 + l32) * PSTR + s * 16 + hl * 8;
      half8 kgh = *(const half8*)&sKh[o1];
      half8 kgl = *(const half8*)&sKl[o1];
      S1 = __builtin_amdgcn_mfma_f32_32x32x16_f16(kgh, qfh[s], S1, 0, 0, 0);
      S1 = __builtin_amdgcn_mfma_f32_32x32x16_f16(kgl, qfh[s], S1, 0, 0, 0);
      S1 = __builtin_amdgcn_mfma_f32_32x32x16_f16(kgh, qfl[s], S1, 0, 0, 0);
    }
    __builtin_amdgcn_s_setprio(0);

    // ---- in-register softmax + pack + scalar denominator ----
    FragSum fs0, fs1, fs2, fs3;
    if (partial && kt == nt - 1) {
      const int rem = cntb - kt * 64 - 4 * hl;
      fs0 = pack8<true>(S0, 0, 0, rem);
      fs1 = pack8<true>(S0, 8, 0, rem);
      fs2 = pack8<true>(S1, 0, 32, rem);
      fs3 = pack8<true>(S1, 8, 32, rem);
    } else {
      fs0 = pack8<false>(S0, 0, 0, 0);
      fs1 = pack8<false>(S0, 8, 0, 0);
      fs2 = pack8<false>(S1, 0, 32, 0);
      fs3 = pack8<false>(S1, 8, 32, 0);
    }
    dsum += (fs0.s + fs1.s) + (fs2.s + fs3.s);

    // ---- prefetch next tile (uniform guard; S0/S1 dead -> fits reg budget) ----
    if (kt + 1 < nt) {
      rKh[0] = *(const short8*)pKh; rKh[1] = *(const short8*)(pKh + 32 * D_);
      rKl[0] = *(const short8*)pKl; rKl[1] = *(const short8*)(pKl + 32 * D_);
      rVh[0] = *(const short8*)pV;  rVh[1] = *(const short8*)(pV + 32 * N_);
      pKh += 64 * D_; pKl += 64 * D_; pV += 64;
    }

    // ---- O += P V (both d-halves) ----
    __builtin_amdgcn_s_setprio(1);
#define PV_STEP(sI, PF)                                                        \
    {                                                                          \
      const int o0 = l32 * PSTR + (sI) * 16 + hl * 8;                          \
      half8 v0 = *(const half8*)&sVh[o0];                                      \
      accO0 = __builtin_amdgcn_mfma_f32_32x32x16_f16((PF), v0, accO0, 0, 0, 0);\
      const int o1 = (32 + l32) * PSTR + (sI) * 16 + hl * 8;                   \
      half8 v1 = *(const half8*)&sVh[o1];                                      \
      accO1 = __builtin_amdgcn_mfma_f32_32x32x16_f16((PF), v1, accO1, 0, 0, 0);\
    }
    PV_STEP(0, fs0.f)
    PV_STEP(1, fs1.f)
    PV_STEP(2, fs2.f)
    PV_STEP(3, fs3.f)
#undef PV_STEP
    __builtin_amdgcn_s_setprio(0);
  }

  // ---- normalize and store (normal stores: L2 write-combining) ----
  float dtot = dsum + __shfl_xor(dsum, 32);
  const size_t obase = (size_t)bh * N_ + qtile * 128 + w * 32;
#pragma unroll
  for (int r = 0; r < 16; ++r) {
    const int row = (r & 3) + 8 * (r >> 2) + 4 * hl;
    float den = __shfl(dtot, row);   // lane 'row' holds q=row's denominator
    float inv = (den > 0.f) ? (1.f / den) : 0.f;
    Og[(obase + row) * D_ + l32]      = accO0[r] * inv;
    Og[(obase + row) * D_ + 32 + l32] = accO1[r] * inv;
  }
}

// --------------- fallback (R9, proven): in-kernel conversions ---------------
__global__ __launch_bounds__(256, 3) void attn_mfma(
    const float* __restrict__ Qg, const float* __restrict__ Kg,
    const float* __restrict__ Vg, const int* __restrict__ maskg,
    float* __restrict__ Og)
{
  const int qtile = blockIdx.x;
  const int bh    = blockIdx.y;
  const int b     = bh >> 3;
  const int tid   = threadIdx.x;
  const int w     = tid >> 6;
  const int lane  = tid & 63;
  const int l32   = lane & 31;
  const int hl    = lane >> 5;
  const int qh    = w >> 1;
  const int kh    = w & 1;

  __shared__ short sKh[64 * PSTR], sKl[64 * PSTR];
  __shared__ short sVh[64 * PSTR], sVl[64 * PSTR];
  __shared__ short sP [64 * PSTR];
  __shared__ float sM[64];

  short8 qfh[4], qfl[4];
  {
    const float* qp = Qg + ((size_t)bh * N_ + qtile * 64 + qh * 32 + l32) * D_ + hl * 8;
#pragma unroll
    for (int s = 0; s < 4; ++s) {
      f32x4 a = *(const f32x4*)(qp + s * 16);
      f32x4 c = *(const f32x4*)(qp + s * 16 + 4);
#pragma unroll
      for (int j = 0; j < 4; ++j) {
        u16 h0 = bfhi(a[j]);
        qfh[s][j] = (short)h0;
        qfl[s][j] = (short)bfhi(a[j] - bf2f(h0));
        u16 h1 = bfhi(c[j]);
        qfh[s][j + 4] = (short)h1;
        qfl[s][j + 4] = (short)bfhi(c[j] - bf2f(h1));
      }
    }
  }
  short8 ones;
#pragma unroll
  for (int j = 0; j < 8; ++j) ones[j] = (short)((l32 == 0) ? 0x3F80 : 0);
  f32x16 accO, accD;
#pragma unroll
  for (int i = 0; i < 16; ++i) { accO[i] = 0.f; accD[i] = 0.f; }
  const size_t kvbase = (size_t)bh * N_ * D_;

  for (int kt = 0; kt < N_ / 64; ++kt) {
    const int k0 = kt * 64;
    __syncthreads();
    {
      const int row = tid >> 2, seg = tid & 3;
      const float* kp = Kg + kvbase + (size_t)(k0 + row) * D_ + seg * 16;
      short8 h0, h1, l0, l1;
#pragma unroll
      for (int i2 = 0; i2 < 2; ++i2) {
        f32x4 t0 = *(const f32x4*)(kp + i2 * 8);
        f32x4 t1 = *(const f32x4*)(kp + i2 * 8 + 4);
#pragma unroll
        for (int j = 0; j < 4; ++j) {
          u16 ha = bfhi(t0[j]); u16 la = bfhi(t0[j] - bf2f(ha));
          u16 hb = bfhi(t1[j]); u16 lb = bfhi(t1[j] - bf2f(hb));
          if (i2 == 0) { h0[j]=(short)ha; l0[j]=(short)la; h0[j+4]=(short)hb; l0[j+4]=(short)lb; }
          else         { h1[j]=(short)ha; l1[j]=(short)la; h1[j+4]=(short)hb; l1[j+4]=(short)lb; }
        }
      }
      *(short8*)&sKh[row * PSTR + seg * 16]     = h0;
      *(short8*)&sKh[row * PSTR + seg * 16 + 8] = h1;
      *(short8*)&sKl[row * PSTR + seg * 16]     = l0;
      *(short8*)&sKl[row * PSTR + seg * 16 + 8] = l1;
    }
    {
      const float* vp = Vg + kvbase + (size_t)(k0 + w * 16) * D_ + lane;
      float vv[16];
#pragma unroll
      for (int kk = 0; kk < 16; ++kk) vv[kk] = vp[(size_t)kk * D_];
      short8 h0, h1, l0, l1;
#pragma unroll
      for (int kk = 0; kk < 8; ++kk) {
        u16 ha = bfhi(vv[kk]);     h0[kk]=(short)ha; l0[kk]=(short)bfhi(vv[kk]-bf2f(ha));
        u16 hb = bfhi(vv[kk + 8]); h1[kk]=(short)hb; l1[kk]=(short)bfhi(vv[kk+8]-bf2f(hb));
      }
      *(short8*)&sVh[lane * PSTR + w * 16]     = h0;
      *(short8*)&sVh[lane * PSTR + w * 16 + 8] = h1;
      *(short8*)&sVl[lane * PSTR + w * 16]     = l0;
      *(short8*)&sVl[lane * PSTR + w * 16 + 8] = l1;
    }
    if (tid < 64) sM[tid] = maskg[b * N_ + k0 + tid] ? 0.f : 1.f;
    __syncthreads();

    f32x16 S;
#pragma unroll
    for (int i = 0; i < 16; ++i) S[i] = 0.f;
#pragma unroll
    for (int s = 0; s < 4; ++s) {
      const int off = (kh * 32 + l32) * PSTR + s * 16 + hl * 8;
      short8 kfh = *(const short8*)&sKh[off];
      short8 kfl = *(const short8*)&sKl[off];
      S = __builtin_amdgcn_mfma_f32_32x32x16_bf16(qfh[s], kfh, S, 0, 0, 0);
      S = __builtin_amdgcn_mfma_f32_32x32x16_bf16(qfl[s], kfh, S, 0, 0, 0);
      S = __builtin_amdgcn_mfma_f32_32x32x16_bf16(qfh[s], kfl, S, 0, 0, 0);
    }
    const float pm = sM[kh * 32 + l32];
#pragma unroll
    for (int r = 0; r < 16; ++r) {
      float x  = S[r] * 0.125f;
      float ax = fminf(fabsf(x), 30.f);
      float z  = __builtin_amdgcn_exp2f(ax * -2.8853900817779268f);
      float nu = (x >= 0.f) ? z : 1.f;
      float e  = nu * __builtin_amdgcn_rcpf(1.f + z) * -28.853900817779268f;
      float p  = __builtin_amdgcn_exp2f(e) * pm;
      const int row = qh * 32 + (r & 3) + 8 * (r >> 2) + 4 * hl;
      sP[row * PSTR + kh * 32 + l32] = (short)bfhi(p);
    }
    __syncthreads();
#pragma unroll
    for (int s = 0; s < 4; ++s) {
      short8 pf  = *(const short8*)&sP[(qh * 32 + l32) * PSTR + s * 16 + hl * 8];
      const int voff = (kh * 32 + l32) * PSTR + s * 16 + hl * 8;
      short8 vfh = *(const short8*)&sVh[voff];
      short8 vfl = *(const short8*)&sVl[voff];
      accO = __builtin_amdgcn_mfma_f32_32x32x16_bf16(pf, vfh, accO, 0, 0, 0);
      accO = __builtin_amdgcn_mfma_f32_32x32x16_bf16(pf, vfl, accO, 0, 0, 0);
      accD = __builtin_amdgcn_mfma_f32_32x32x16_bf16(pf, ones, accD, 0, 0, 0);
    }
  }
  const size_t obase = (size_t)bh * N_ + qtile * 64 + qh * 32;
#pragma unroll
  for (int r = 0; r < 16; ++r) {
    float den = __shfl(accD[r], lane & 32);
    float inv = (den > 0.f) ? (1.f / den) : 0.f;
    const int row = (r & 3) + 8 * (r >> 2) + 4 * hl;
    Og[(obase + row) * D_ + kh * 32 + l32] = accO[r] * inv;
  }
}

extern "C" void kernel_launch(void* const* d_in, const int* in_sizes, int n_in,
                              void* d_out, int out_size, void* d_ws, size_t ws_size,
                              hipStream_t stream) {
  const float* Q = (const float*)d_in[0];
  const float* K = (const float*)d_in[1];
  const float* V = (const float*)d_in[2];
  const int* mask = (const int*)d_in[3];
  float* out = (float*)d_out;
  dim3 block(256);
  if (ws_size >= (size_t)WS_NEED) {
    u16* wsp  = (u16*)d_ws;
    u16* Khi  = wsp;
    u16* Klo  = wsp + ELEMS;
    u16* VThi = wsp + 2 * (size_t)ELEMS;
    int* cntp = (int*)(wsp + 3 * (size_t)ELEMS);
    conv_kv3<<<dim3(32, 64), block, 0, stream>>>(K, V, mask, Khi, Klo, VThi, cntp);
    attn_mfma9<<<dim3(1024), block, 0, stream>>>(Q, Khi, Klo, VThi, cntp, out);
  } else {
    attn_mfma<<<dim3(32, 64), block, 0, stream>>>(Q, K, V, mask, out);
  }
}

// Round 11
// 254.330 us; speedup vs baseline: 1.1163x; 1.1163x over previous
//
#include <hip/hip_runtime.h>

typedef __attribute__((ext_vector_type(8))) short short8;
typedef __attribute__((ext_vector_type(8))) _Float16 half8;
typedef __attribute__((ext_vector_type(2))) __fp16 fp16x2;
typedef __attribute__((ext_vector_type(2))) unsigned int uint2v;
typedef __attribute__((ext_vector_type(16))) float f32x16;
typedef __attribute__((ext_vector_type(4))) float f32x4;
typedef __attribute__((ext_vector_type(4))) unsigned short u16x4;
typedef __attribute__((ext_vector_type(8))) unsigned short u16x8;
typedef unsigned int u32;
typedef unsigned short u16;

#define B_ 8
#define H_ 8
#define N_ 2048
#define D_ 64
#define PSTR 72   // LDS row stride (shorts)
#define TSTR 66   // conv transpose LDS stride (floats)
#define ELEMS 8388608             // B*H*N*D
#define WS_NEED ((48ull << 20) + 4096ull)

static __device__ inline u16 bfhi(float x) {
  u32 u = __float_as_uint(x);
  return (u16)((u + 0x7FFFu + ((u >> 16) & 1u)) >> 16);
}
static __device__ inline float bf2f(u16 h) { return __uint_as_float((u32)h << 16); }
static __device__ inline u16 h2u(_Float16 h) { union { _Float16 f; u16 u; } c; c.f = h; return c.u; }

static __device__ __forceinline__ u32 pkrtz_u32(float a, float b) {
  union { fp16x2 h; u32 u; } c;
  c.h = __builtin_amdgcn_cvt_pkrtz(a, b);
  return c.u;
}

// softmax numerator p = exp(10*tanh(s/8) - 10) = exp2(-28.85/(1+exp2(s*.3607)))
template <bool TAIL>
static __device__ __forceinline__ float pnum(float s, int key, int rem) {
  float t = __builtin_amdgcn_exp2f(s * 0.36067376022224087f);
  float e = __builtin_amdgcn_rcpf(1.f + t) * -28.853900817779268f;
  if (TAIL) e = (key < rem) ? e : -16384.f;
  return __builtin_amdgcn_exp2f(e);
}

// quads: regs 4q..4q+3 cover keys 8q+4hl..4hl+3. A-frag needs k=32h+16g+8hl+j.
// hl=0: own even-quad then partner even-quad; hl=1: partner odd-quad then own
// odd-quad -> one permlane32_swap pair per 8-key group.
static __device__ __forceinline__ half8 pack_frag(
    float qa, float qb, float qc, float qd,
    float qe, float qf, float qg, float qh) {
  u32 E0 = pkrtz_u32(qa, qb);
  u32 E1 = pkrtz_u32(qc, qd);
  u32 O0 = pkrtz_u32(qe, qf);
  u32 O1 = pkrtz_u32(qg, qh);
  uint2v w0 = __builtin_amdgcn_permlane32_swap(E0, O0, false, false);
  uint2v w1 = __builtin_amdgcn_permlane32_swap(E1, O1, false, false);
  union { u32 u[4]; half8 v; } c;
  c.u[0] = w0[0]; c.u[1] = w1[0]; c.u[2] = w0[1]; c.u[3] = w1[1];
  return c.v;
}

struct FragSum { half8 f; float s; };   // by-value, no address-taken arrays

// 8 consecutive S elements (rbase..rbase+7) -> one PV A-frag + partial row-sum.
template <bool TAIL>
static __device__ __forceinline__ FragSum pack8(
    f32x16 S, int rbase, int koff, int rem) {
#define KEYI(i) ((((rbase) + (i)) & 3) + 8 * (((rbase) + (i)) >> 2) + (koff))
  float pA = pnum<TAIL>(S[rbase + 0], KEYI(0), rem);
  float pB = pnum<TAIL>(S[rbase + 1], KEYI(1), rem);
  float pC = pnum<TAIL>(S[rbase + 2], KEYI(2), rem);
  float pD = pnum<TAIL>(S[rbase + 3], KEYI(3), rem);
  float pE = pnum<TAIL>(S[rbase + 4], KEYI(4), rem);
  float pF = pnum<TAIL>(S[rbase + 5], KEYI(5), rem);
  float pG = pnum<TAIL>(S[rbase + 6], KEYI(6), rem);
  float pH = pnum<TAIL>(S[rbase + 7], KEYI(7), rem);
#undef KEYI
  FragSum o;
  o.f = pack_frag(pA, pB, pC, pD, pE, pF, pG, pH);
  o.s = ((pA + pB) + (pC + pD)) + ((pE + pF) + (pG + pH));
  return o;
}

// ---- fused prepass: in-block mask scan + compacted gather + convert -------
// K -> f16 (hi,lo) dense rows; V -> [bh][d][key] f16. cnt[b] written by h==0,kt==0.
__global__ __launch_bounds__(256) void conv_kv3(
    const float* __restrict__ K, const float* __restrict__ V,
    const int* __restrict__ maskg,
    u16* __restrict__ Khi, u16* __restrict__ Klo, u16* __restrict__ VThi,
    int* __restrict__ cnt) {
  const int kt = blockIdx.x, bh = blockIdx.y, b = bh >> 3, tid = threadIdx.x;
  const int lane = tid & 63, wv = tid >> 6;
  __shared__ float sT[64 * TSTR];
  __shared__ int sIdx[64];
  __shared__ int wsum[4];
  // redundant per-block scan of this batch's 2048-key mask (cheap, kills a launch)
  const int n0 = tid * 8;
  u32 bits = 0; int c = 0;
#pragma unroll
  for (int i = 0; i < 8; ++i)
    if (maskg[b * N_ + n0 + i] == 0) { bits |= (1u << i); ++c; }  // mask==0 kept
  int inc = c;
#pragma unroll
  for (int off = 1; off < 64; off <<= 1) {
    int v = __shfl_up(inc, off);
    if (lane >= off) inc += v;
  }
  if (lane == 63) wsum[wv] = inc;
  if (tid < 64) sIdx[tid] = -1;
  __syncthreads();
  const int cntb = wsum[0] + wsum[1] + wsum[2] + wsum[3];
  int o = inc - c;
#pragma unroll
  for (int k2 = 0; k2 < 4; ++k2) if (k2 < wv) o += wsum[k2];
  const int k0 = kt * 64;
#pragma unroll
  for (int i = 0; i < 8; ++i)
    if (bits & (1u << i)) {
      if (o >= k0 && o < k0 + 64) sIdx[o - k0] = n0 + i;
      ++o;
    }
  if (kt == 0 && (bh & 7) == 0 && tid == 0) cnt[b] = cntb;
  __syncthreads();
  const int nt = (cntb + 63) >> 6;
  if (kt >= nt) return;

  const size_t ibh = (size_t)bh * N_ * D_;
  const size_t okb = ibh + (size_t)kt * 64 * D_;   // compacted K row base
#pragma unroll
  for (int cc = 0; cc < 2; ++cc) {
    const int ci = tid + cc * 256, row = ci >> 3, seg = ci & 7;
    const int n = sIdx[row];
    f32x4 a, b2, va, vb2;
    if (n >= 0) {
      const float* kp = K + ibh + (size_t)n * D_ + seg * 8;
      a  = __builtin_nontemporal_load((const f32x4*)kp);
      b2 = __builtin_nontemporal_load((const f32x4*)(kp + 4));
      const float* vp = V + ibh + (size_t)n * D_ + seg * 8;
      va  = __builtin_nontemporal_load((const f32x4*)vp);
      vb2 = __builtin_nontemporal_load((const f32x4*)(vp + 4));
    } else {
#pragma unroll
      for (int j = 0; j < 4; ++j) { a[j] = 0.f; b2[j] = 0.f; va[j] = 0.f; vb2[j] = 0.f; }
    }
    u16x8 h, l;
#pragma unroll
    for (int j = 0; j < 4; ++j) {
      _Float16 h0 = (_Float16)a[j];
      h[j] = h2u(h0); l[j] = h2u((_Float16)(a[j] - (float)h0));
      _Float16 h1 = (_Float16)b2[j];
      h[j + 4] = h2u(h1); l[j + 4] = h2u((_Float16)(b2[j] - (float)h1));
    }
    *(u16x8*)&Khi[okb + row * D_ + seg * 8] = h;
    *(u16x8*)&Klo[okb + row * D_ + seg * 8] = l;
    *(f32x4*)&sT[row * TSTR + seg * 8]     = va;
    *(f32x4*)&sT[row * TSTR + seg * 8 + 4] = vb2;
  }
  __syncthreads();
  // 4x4 in-register transpose: 4 vector row-reads, 4 coalesced 8B col-writes.
  const int key0 = (tid & 15) * 4, d0 = (tid >> 4) * 4;
  f32x4 r0 = *(const f32x4*)&sT[(key0 + 0) * TSTR + d0];
  f32x4 r1 = *(const f32x4*)&sT[(key0 + 1) * TSTR + d0];
  f32x4 r2 = *(const f32x4*)&sT[(key0 + 2) * TSTR + d0];
  f32x4 r3 = *(const f32x4*)&sT[(key0 + 3) * TSTR + d0];
  const size_t ob = (size_t)bh * D_ * N_ + (size_t)kt * 64 + key0;
#pragma unroll
  for (int j = 0; j < 4; ++j) {
    u16x4 ov;
    ov[0] = h2u((_Float16)r0[j]); ov[1] = h2u((_Float16)r1[j]);
    ov[2] = h2u((_Float16)r2[j]); ov[3] = h2u((_Float16)r3[j]);
    *(u16x4*)&VThi[ob + (size_t)(d0 + j) * N_] = ov;
  }
}

// -- main kernel: swapped QK^T, in-reg softmax, reg-prefetch, XCD-homed bh ---
// Prefetch addressing = R8's clamped per-tile recompute (proven spill-free,
// WRITE=91MB); R9/R10's persistent pointer trio spilled (WRITE=608MB).
__global__ __launch_bounds__(256, 4) void attn_mfma10(
    const float* __restrict__ Qg,
    const u16* __restrict__ Khi, const u16* __restrict__ Klo,
    const u16* __restrict__ VThi,
    const int* __restrict__ cnt, float* __restrict__ Og)
{
  // XCD-homing swizzle: linear blk -> XCD blk&7 (round-robin dispatch). All
  // 16 qtile-blocks of a bh live on ONE XCD so K/V is fetched once into its
  // L2 (8 bh * 384 KB = 3 MB < 4 MB). Q uses non-temporal LOADS so its
  // stream doesn't evict the shared K/V set (FETCH 288->134MB, R9-R10).
  const int blk = blockIdx.x;
  const int xcd = blk & 7, slot = blk >> 3;
  const int bh = ((slot >> 4) << 3) | xcd;   // 8 bh per XCD
  const int qtile = slot & 15;               // 0..15 (128 q-rows each)
  const int b = bh >> 3;
  const int tid = threadIdx.x, w = tid >> 6, lane = tid & 63;
  const int l32 = lane & 31, hl = lane >> 5;
  const int cntb = cnt[b];
  const int nt = (cntb + 63) >> 6;
  const bool partial = (cntb & 63) != 0;

  __shared__ short sKh[64 * PSTR], sKl[64 * PSTR];
  __shared__ short sVh[64 * PSTR];

  // ---- Q fragments (f16 hi/lo): lane holds Q[q=w*32+l32][k=s*16+hl*8+j] ----
  half8 qfh[4], qfl[4];
  {
    const float* qp = Qg + ((size_t)bh * N_ + qtile * 128 + w * 32 + l32) * D_ + hl * 8;
#pragma unroll
    for (int s = 0; s < 4; ++s) {
      f32x4 a = __builtin_nontemporal_load((const f32x4*)(qp + s * 16));
      f32x4 c = __builtin_nontemporal_load((const f32x4*)(qp + s * 16 + 4));
#pragma unroll
      for (int j = 0; j < 4; ++j) {
        _Float16 h0 = (_Float16)a[j];
        qfh[s][j] = h0; qfl[s][j] = (_Float16)(a[j] - (float)h0);
        _Float16 h1 = (_Float16)c[j];
        qfh[s][j + 4] = h1; qfl[s][j + 4] = (_Float16)(c[j] - (float)h1);
      }
    }
  }

  f32x16 accO0, accO1;
#pragma unroll
  for (int i = 0; i < 16; ++i) { accO0[i] = 0.f; accO1[i] = 0.f; }
  float dsum = 0.f;

  const size_t kvb = (size_t)bh * N_ * D_;

  // ---- prologue: prefetch tile 0 into registers ----
  short8 rKh[2], rKl[2], rVh[2];
#pragma unroll
  for (int cc = 0; cc < 2; ++cc) {
    const int ci = tid + cc * 256, row = ci >> 3, seg = ci & 7;
    rKh[cc] = *(const short8*)&Khi[kvb + (size_t)row * D_ + seg * 8];
    rKl[cc] = *(const short8*)&Klo[kvb + (size_t)row * D_ + seg * 8];
    rVh[cc] = *(const short8*)&VThi[kvb + (size_t)row * N_ + seg * 8];
  }

  for (int kt = 0; kt < nt; ++kt) {
    __syncthreads();   // (A) prev tile's sK/sV reads complete

    // ---- staging: write prefetched regs to LDS (b128 ds_writes) ----
#pragma unroll
    for (int cc = 0; cc < 2; ++cc) {
      const int ci = tid + cc * 256, row = ci >> 3, seg = ci & 7;
      const int lofs = row * PSTR + seg * 8;
      *(short8*)&sKh[lofs] = rKh[cc];
      *(short8*)&sKl[lofs] = rKl[cc];
      *(short8*)&sVh[lofs] = rVh[cc];
    }
    __syncthreads();   // (B)

    // ---- S^T = K Q^T: C col = q-row (l32), C rows = keys (in-register) ----
    f32x16 S0, S1;
#pragma unroll
    for (int i = 0; i < 16; ++i) { S0[i] = 0.f; S1[i] = 0.f; }
    __builtin_amdgcn_s_setprio(1);
#pragma unroll
    for (int s = 0; s < 4; ++s) {
      const int o0 = l32 * PSTR + s * 16 + hl * 8;
      half8 kfh = *(const half8*)&sKh[o0];
      half8 kfl = *(const half8*)&sKl[o0];
      S0 = __builtin_amdgcn_mfma_f32_32x32x16_f16(kfh, qfh[s], S0, 0, 0, 0);
      S0 = __builtin_amdgcn_mfma_f32_32x32x16_f16(kfl, qfh[s], S0, 0, 0, 0);
      S0 = __builtin_amdgcn_mfma_f32_32x32x16_f16(kfh, qfl[s], S0, 0, 0, 0);
      const int o1 = (32 + l32) * PSTR + s * 16 + hl * 8;
      half8 kgh = *(const half8*)&sKh[o1];
      half8 kgl = *(const half8*)&sKl[o1];
      S1 = __builtin_amdgcn_mfma_f32_32x32x16_f16(kgh, qfh[s], S1, 0, 0, 0);
      S1 = __builtin_amdgcn_mfma_f32_32x32x16_f16(kgl, qfh[s], S1, 0, 0, 0);
      S1 = __builtin_amdgcn_mfma_f32_32x32x16_f16(kgh, qfl[s], S1, 0, 0, 0);
    }
    __builtin_amdgcn_s_setprio(0);

    // ---- in-register softmax + pack + scalar denominator ----
    FragSum fs0, fs1, fs2, fs3;
    if (partial && kt == nt - 1) {
      const int rem = cntb - kt * 64 - 4 * hl;
      fs0 = pack8<true>(S0, 0, 0, rem);
      fs1 = pack8<true>(S0, 8, 0, rem);
      fs2 = pack8<true>(S1, 0, 32, rem);
      fs3 = pack8<true>(S1, 8, 32, rem);
    } else {
      fs0 = pack8<false>(S0, 0, 0, 0);
      fs1 = pack8<false>(S0, 8, 0, 0);
      fs2 = pack8<false>(S1, 0, 32, 0);
      fs3 = pack8<false>(S1, 8, 32, 0);
    }
    dsum += (fs0.s + fs1.s) + (fs2.s + fs3.s);

    // ---- prefetch next tile (clamped recompute; S0/S1 dead -> fits budget) ----
    {
      const int k0n = (kt + 1 < nt ? kt + 1 : kt) * 64;
#pragma unroll
      for (int cc = 0; cc < 2; ++cc) {
        const int ci = tid + cc * 256, row = ci >> 3, seg = ci & 7;
        rKh[cc] = *(const short8*)&Khi[kvb + (size_t)(k0n + row) * D_ + seg * 8];
        rKl[cc] = *(const short8*)&Klo[kvb + (size_t)(k0n + row) * D_ + seg * 8];
        rVh[cc] = *(const short8*)&VThi[kvb + (size_t)row * N_ + k0n + seg * 8];
      }
    }

    // ---- O += P V (both d-halves) ----
    __builtin_amdgcn_s_setprio(1);
#define PV_STEP(sI, PF)                                                        \
    {                                                                          \
      const int o0 = l32 * PSTR + (sI) * 16 + hl * 8;                          \
      half8 v0 = *(const half8*)&sVh[o0];                                      \
      accO0 = __builtin_amdgcn_mfma_f32_32x32x16_f16((PF), v0, accO0, 0, 0, 0);\
      const int o1 = (32 + l32) * PSTR + (sI) * 16 + hl * 8;                   \
      half8 v1 = *(const half8*)&sVh[o1];                                      \
      accO1 = __builtin_amdgcn_mfma_f32_32x32x16_f16((PF), v1, accO1, 0, 0, 0);\
    }
    PV_STEP(0, fs0.f)
    PV_STEP(1, fs1.f)
    PV_STEP(2, fs2.f)
    PV_STEP(3, fs3.f)
#undef PV_STEP
    __builtin_amdgcn_s_setprio(0);
  }

  // ---- normalize and store (normal stores: L2 write-combining) ----
  float dtot = dsum + __shfl_xor(dsum, 32);
  const size_t obase = (size_t)bh * N_ + qtile * 128 + w * 32;
#pragma unroll
  for (int r = 0; r < 16; ++r) {
    const int row = (r & 3) + 8 * (r >> 2) + 4 * hl;
    float den = __shfl(dtot, row);   // lane 'row' holds q=row's denominator
    float inv = (den > 0.f) ? (1.f / den) : 0.f;
    Og[(obase + row) * D_ + l32]      = accO0[r] * inv;
    Og[(obase + row) * D_ + 32 + l32] = accO1[r] * inv;
  }
}

// --------------- fallback (R9, proven): in-kernel conversions ---------------
__global__ __launch_bounds__(256, 3) void attn_mfma(
    const float* __restrict__ Qg, const float* __restrict__ Kg,
    const float* __restrict__ Vg, const int* __restrict__ maskg,
    float* __restrict__ Og)
{
  const int qtile = blockIdx.x;
  const int bh    = blockIdx.y;
  const int b     = bh >> 3;
  const int tid   = threadIdx.x;
  const int w     = tid >> 6;
  const int lane  = tid & 63;
  const int l32   = lane & 31;
  const int hl    = lane >> 5;
  const int qh    = w >> 1;
  const int kh    = w & 1;

  __shared__ short sKh[64 * PSTR], sKl[64 * PSTR];
  __shared__ short sVh[64 * PSTR], sVl[64 * PSTR];
  __shared__ short sP [64 * PSTR];
  __shared__ float sM[64];

  short8 qfh[4], qfl[4];
  {
    const float* qp = Qg + ((size_t)bh * N_ + qtile * 64 + qh * 32 + l32) * D_ + hl * 8;
#pragma unroll
    for (int s = 0; s < 4; ++s) {
      f32x4 a = *(const f32x4*)(qp + s * 16);
      f32x4 c = *(const f32x4*)(qp + s * 16 + 4);
#pragma unroll
      for (int j = 0; j < 4; ++j) {
        u16 h0 = bfhi(a[j]);
        qfh[s][j] = (short)h0;
        qfl[s][j] = (short)bfhi(a[j] - bf2f(h0));
        u16 h1 = bfhi(c[j]);
        qfh[s][j + 4] = (short)h1;
        qfl[s][j + 4] = (short)bfhi(c[j] - bf2f(h1));
      }
    }
  }
  short8 ones;
#pragma unroll
  for (int j = 0; j < 8; ++j) ones[j] = (short)((l32 == 0) ? 0x3F80 : 0);
  f32x16 accO, accD;
#pragma unroll
  for (int i = 0; i < 16; ++i) { accO[i] = 0.f; accD[i] = 0.f; }
  const size_t kvbase = (size_t)bh * N_ * D_;

  for (int kt = 0; kt < N_ / 64; ++kt) {
    const int k0 = kt * 64;
    __syncthreads();
    {
      const int row = tid >> 2, seg = tid & 3;
      const float* kp = Kg + kvbase + (size_t)(k0 + row) * D_ + seg * 16;
      short8 h0, h1, l0, l1;
#pragma unroll
      for (int i2 = 0; i2 < 2; ++i2) {
        f32x4 t0 = *(const f32x4*)(kp + i2 * 8);
        f32x4 t1 = *(const f32x4*)(kp + i2 * 8 + 4);
#pragma unroll
        for (int j = 0; j < 4; ++j) {
          u16 ha = bfhi(t0[j]); u16 la = bfhi(t0[j] - bf2f(ha));
          u16 hb = bfhi(t1[j]); u16 lb = bfhi(t1[j] - bf2f(hb));
          if (i2 == 0) { h0[j]=(short)ha; l0[j]=(short)la; h0[j+4]=(short)hb; l0[j+4]=(short)lb; }
          else         { h1[j]=(short)ha; l1[j]=(short)la; h1[j+4]=(short)hb; l1[j+4]=(short)lb; }
        }
      }
      *(short8*)&sKh[row * PSTR + seg * 16]     = h0;
      *(short8*)&sKh[row * PSTR + seg * 16 + 8] = h1;
      *(short8*)&sKl[row * PSTR + seg * 16]     = l0;
      *(short8*)&sKl[row * PSTR + seg * 16 + 8] = l1;
    }
    {
      const float* vp = Vg + kvbase + (size_t)(k0 + w * 16) * D_ + lane;
      float vv[16];
#pragma unroll
      for (int kk = 0; kk < 16; ++kk) vv[kk] = vp[(size_t)kk * D_];
      short8 h0, h1, l0, l1;
#pragma unroll
      for (int kk = 0; kk < 8; ++kk) {
        u16 ha = bfhi(vv[kk]);     h0[kk]=(short)ha; l0[kk]=(short)bfhi(vv[kk]-bf2f(ha));
        u16 hb = bfhi(vv[kk + 8]); h1[kk]=(short)hb; l1[kk]=(short)bfhi(vv[kk+8]-bf2f(hb));
      }
      *(short8*)&sVh[lane * PSTR + w * 16]     = h0;
      *(short8*)&sVh[lane * PSTR + w * 16 + 8] = h1;
      *(short8*)&sVl[lane * PSTR + w * 16]     = l0;
      *(short8*)&sVl[lane * PSTR + w * 16 + 8] = l1;
    }
    if (tid < 64) sM[tid] = maskg[b * N_ + k0 + tid] ? 0.f : 1.f;
    __syncthreads();

    f32x16 S;
#pragma unroll
    for (int i = 0; i < 16; ++i) S[i] = 0.f;
#pragma unroll
    for (int s = 0; s < 4; ++s) {
      const int off = (kh * 32 + l32) * PSTR + s * 16 + hl * 8;
      short8 kfh = *(const short8*)&sKh[off];
      short8 kfl = *(const short8*)&sKl[off];
      S = __builtin_amdgcn_mfma_f32_32x32x16_bf16(qfh[s], kfh, S, 0, 0, 0);
      S = __builtin_amdgcn_mfma_f32_32x32x16_bf16(qfl[s], kfh, S, 0, 0, 0);
      S = __builtin_amdgcn_mfma_f32_32x32x16_bf16(qfh[s], kfl, S, 0, 0, 0);
    }
    const float pm = sM[kh * 32 + l32];
#pragma unroll
    for (int r = 0; r < 16; ++r) {
      float x  = S[r] * 0.125f;
      float ax = fminf(fabsf(x), 30.f);
      float z  = __builtin_amdgcn_exp2f(ax * -2.8853900817779268f);
      float nu = (x >= 0.f) ? z : 1.f;
      float e  = nu * __builtin_amdgcn_rcpf(1.f + z) * -28.853900817779268f;
      float p  = __builtin_amdgcn_exp2f(e) * pm;
      const int row = qh * 32 + (r & 3) + 8 * (r >> 2) + 4 * hl;
      sP[row * PSTR + kh * 32 + l32] = (short)bfhi(p);
    }
    __syncthreads();
#pragma unroll
    for (int s = 0; s < 4; ++s) {
      short8 pf  = *(const short8*)&sP[(qh * 32 + l32) * PSTR + s * 16 + hl * 8];
      const int voff = (kh * 32 + l32) * PSTR + s * 16 + hl * 8;
      short8 vfh = *(const short8*)&sVh[voff];
      short8 vfl = *(const short8*)&sVl[voff];
      accO = __builtin_amdgcn_mfma_f32_32x32x16_bf16(pf, vfh, accO, 0, 0, 0);
      accO = __builtin_amdgcn_mfma_f32_32x32x16_bf16(pf, vfl, accO, 0, 0, 0);
      accD = __builtin_amdgcn_mfma_f32_32x32x16_bf16(pf, ones, accD, 0, 0, 0);
    }
  }
  const size_t obase = (size_t)bh * N_ + qtile * 64 + qh * 32;
#pragma unroll
  for (int r = 0; r < 16; ++r) {
    float den = __shfl(accD[r], lane & 32);
    float inv = (den > 0.f) ? (1.f / den) : 0.f;
    const int row = (r & 3) + 8 * (r >> 2) + 4 * hl;
    Og[(obase + row) * D_ + kh * 32 + l32] = accO[r] * inv;
  }
}

extern "C" void kernel_launch(void* const* d_in, const int* in_sizes, int n_in,
                              void* d_out, int out_size, void* d_ws, size_t ws_size,
                              hipStream_t stream) {
  const float* Q = (const float*)d_in[0];
  const float* K = (const float*)d_in[1];
  const float* V = (const float*)d_in[2];
  const int* mask = (const int*)d_in[3];
  float* out = (float*)d_out;
  dim3 block(256);
  if (ws_size >= (size_t)WS_NEED) {
    u16* wsp  = (u16*)d_ws;
    u16* Khi  = wsp;
    u16* Klo  = wsp + ELEMS;
    u16* VThi = wsp + 2 * (size_t)ELEMS;
    int* cntp = (int*)(wsp + 3 * (size_t)ELEMS);
    conv_kv3<<<dim3(32, 64), block, 0, stream>>>(K, V, mask, Khi, Klo, VThi, cntp);
    attn_mfma10<<<dim3(1024), block, 0, stream>>>(Q, Khi, Klo, VThi, cntp, out);
  } else {
    attn_mfma<<<dim3(32, 64), block, 0, stream>>>(Q, K, V, mask, out);
  }
}

// Round 12
// 238.115 us; speedup vs baseline: 1.1923x; 1.0681x over previous
//
#include <hip/hip_runtime.h>

typedef __attribute__((ext_vector_type(8))) short short8;
typedef __attribute__((ext_vector_type(8))) _Float16 half8;
typedef __attribute__((ext_vector_type(2))) __fp16 fp16x2;
typedef __attribute__((ext_vector_type(2))) unsigned int uint2v;
typedef __attribute__((ext_vector_type(16))) float f32x16;
typedef __attribute__((ext_vector_type(4))) float f32x4;
typedef __attribute__((ext_vector_type(4))) unsigned short u16x4;
typedef __attribute__((ext_vector_type(8))) unsigned short u16x8;
typedef unsigned int u32;
typedef unsigned short u16;

#define B_ 8
#define H_ 8
#define N_ 2048
#define D_ 64
#define PSTR 72   // LDS row stride (shorts)
#define TSTR 66   // conv transpose LDS stride (floats)
#define ELEMS 8388608             // B*H*N*D
#define WS_NEED ((32ull << 20) + 4096ull)

static __device__ inline u16 bfhi(float x) {
  u32 u = __float_as_uint(x);
  return (u16)((u + 0x7FFFu + ((u >> 16) & 1u)) >> 16);
}
static __device__ inline float bf2f(u16 h) { return __uint_as_float((u32)h << 16); }
static __device__ inline u16 h2u(_Float16 h) { union { _Float16 f; u16 u; } c; c.f = h; return c.u; }

static __device__ __forceinline__ u32 pkrtz_u32(float a, float b) {
  union { fp16x2 h; u32 u; } c;
  c.h = __builtin_amdgcn_cvt_pkrtz(a, b);
  return c.u;
}

// softmax numerator p = exp(10*tanh(s/8) - 10) = exp2(-28.85/(1+exp2(s*.3607)))
template <bool TAIL>
static __device__ __forceinline__ float pnum(float s, int key, int rem) {
  float t = __builtin_amdgcn_exp2f(s * 0.36067376022224087f);
  float e = __builtin_amdgcn_rcpf(1.f + t) * -28.853900817779268f;
  if (TAIL) e = (key < rem) ? e : -16384.f;
  return __builtin_amdgcn_exp2f(e);
}

// quads: regs 4q..4q+3 cover keys 8q+4hl..4hl+3. A-frag needs k=32h+16g+8hl+j.
// hl=0: own even-quad then partner even-quad; hl=1: partner odd-quad then own
// odd-quad -> one permlane32_swap pair per 8-key group.
static __device__ __forceinline__ half8 pack_frag(
    float qa, float qb, float qc, float qd,
    float qe, float qf, float qg, float qh) {
  u32 E0 = pkrtz_u32(qa, qb);
  u32 E1 = pkrtz_u32(qc, qd);
  u32 O0 = pkrtz_u32(qe, qf);
  u32 O1 = pkrtz_u32(qg, qh);
  uint2v w0 = __builtin_amdgcn_permlane32_swap(E0, O0, false, false);
  uint2v w1 = __builtin_amdgcn_permlane32_swap(E1, O1, false, false);
  union { u32 u[4]; half8 v; } c;
  c.u[0] = w0[0]; c.u[1] = w1[0]; c.u[2] = w0[1]; c.u[3] = w1[1];
  return c.v;
}

struct FragSum { half8 f; float s; };   // by-value, no address-taken arrays

// 8 consecutive S elements (rbase..rbase+7) -> one PV A-frag + partial row-sum.
template <bool TAIL>
static __device__ __forceinline__ FragSum pack8(
    f32x16 S, int rbase, int koff, int rem) {
#define KEYI(i) ((((rbase) + (i)) & 3) + 8 * (((rbase) + (i)) >> 2) + (koff))
  float pA = pnum<TAIL>(S[rbase + 0], KEYI(0), rem);
  float pB = pnum<TAIL>(S[rbase + 1], KEYI(1), rem);
  float pC = pnum<TAIL>(S[rbase + 2], KEYI(2), rem);
  float pD = pnum<TAIL>(S[rbase + 3], KEYI(3), rem);
  float pE = pnum<TAIL>(S[rbase + 4], KEYI(4), rem);
  float pF = pnum<TAIL>(S[rbase + 5], KEYI(5), rem);
  float pG = pnum<TAIL>(S[rbase + 6], KEYI(6), rem);
  float pH = pnum<TAIL>(S[rbase + 7], KEYI(7), rem);
#undef KEYI
  FragSum o;
  o.f = pack_frag(pA, pB, pC, pD, pE, pF, pG, pH);
  o.s = ((pA + pB) + (pC + pD)) + ((pE + pF) + (pG + pH));
  return o;
}

// ---- fused prepass: in-block mask scan + compacted gather + convert -------
// K -> f16 RTN dense rows (hi only: 2-term QK); V -> [bh][d][key] f16.
__global__ __launch_bounds__(256) void conv_kv4(
    const float* __restrict__ K, const float* __restrict__ V,
    const int* __restrict__ maskg,
    u16* __restrict__ Khi, u16* __restrict__ VThi,
    int* __restrict__ cnt) {
  const int kt = blockIdx.x, bh = blockIdx.y, b = bh >> 3, tid = threadIdx.x;
  const int lane = tid & 63, wv = tid >> 6;
  __shared__ float sT[64 * TSTR];
  __shared__ int sIdx[64];
  __shared__ int wsum[4];
  // redundant per-block scan of this batch's 2048-key mask (cheap, kills a launch)
  const int n0 = tid * 8;
  u32 bits = 0; int c = 0;
#pragma unroll
  for (int i = 0; i < 8; ++i)
    if (maskg[b * N_ + n0 + i] == 0) { bits |= (1u << i); ++c; }  // mask==0 kept
  int inc = c;
#pragma unroll
  for (int off = 1; off < 64; off <<= 1) {
    int v = __shfl_up(inc, off);
    if (lane >= off) inc += v;
  }
  if (lane == 63) wsum[wv] = inc;
  if (tid < 64) sIdx[tid] = -1;
  __syncthreads();
  const int cntb = wsum[0] + wsum[1] + wsum[2] + wsum[3];
  int o = inc - c;
#pragma unroll
  for (int k2 = 0; k2 < 4; ++k2) if (k2 < wv) o += wsum[k2];
  const int k0 = kt * 64;
#pragma unroll
  for (int i = 0; i < 8; ++i)
    if (bits & (1u << i)) {
      if (o >= k0 && o < k0 + 64) sIdx[o - k0] = n0 + i;
      ++o;
    }
  if (kt == 0 && (bh & 7) == 0 && tid == 0) cnt[b] = cntb;
  __syncthreads();
  const int nt = (cntb + 63) >> 6;
  if (kt >= nt) return;

  const size_t ibh = (size_t)bh * N_ * D_;
  const size_t okb = ibh + (size_t)kt * 64 * D_;   // compacted K row base
#pragma unroll
  for (int cc = 0; cc < 2; ++cc) {
    const int ci = tid + cc * 256, row = ci >> 3, seg = ci & 7;
    const int n = sIdx[row];
    f32x4 a, b2, va, vb2;
    if (n >= 0) {
      const float* kp = K + ibh + (size_t)n * D_ + seg * 8;
      a  = __builtin_nontemporal_load((const f32x4*)kp);
      b2 = __builtin_nontemporal_load((const f32x4*)(kp + 4));
      const float* vp = V + ibh + (size_t)n * D_ + seg * 8;
      va  = __builtin_nontemporal_load((const f32x4*)vp);
      vb2 = __builtin_nontemporal_load((const f32x4*)(vp + 4));
    } else {
#pragma unroll
      for (int j = 0; j < 4; ++j) { a[j] = 0.f; b2[j] = 0.f; va[j] = 0.f; vb2[j] = 0.f; }
    }
    u16x8 h;
#pragma unroll
    for (int j = 0; j < 4; ++j) {
      h[j]     = h2u((_Float16)a[j]);      // RTN f16
      h[j + 4] = h2u((_Float16)b2[j]);
    }
    *(u16x8*)&Khi[okb + row * D_ + seg * 8] = h;
    *(f32x4*)&sT[row * TSTR + seg * 8]     = va;
    *(f32x4*)&sT[row * TSTR + seg * 8 + 4] = vb2;
  }
  __syncthreads();
  // 4x4 in-register transpose: 4 vector row-reads, 4 coalesced 8B col-writes.
  const int key0 = (tid & 15) * 4, d0 = (tid >> 4) * 4;
  f32x4 r0 = *(const f32x4*)&sT[(key0 + 0) * TSTR + d0];
  f32x4 r1 = *(const f32x4*)&sT[(key0 + 1) * TSTR + d0];
  f32x4 r2 = *(const f32x4*)&sT[(key0 + 2) * TSTR + d0];
  f32x4 r3 = *(const f32x4*)&sT[(key0 + 3) * TSTR + d0];
  const size_t ob = (size_t)bh * D_ * N_ + (size_t)kt * 64 + key0;
#pragma unroll
  for (int j = 0; j < 4; ++j) {
    u16x4 ov;
    ov[0] = h2u((_Float16)r0[j]); ov[1] = h2u((_Float16)r1[j]);
    ov[2] = h2u((_Float16)r2[j]); ov[3] = h2u((_Float16)r3[j]);
    *(u16x4*)&VThi[ob + (size_t)(d0 + j) * N_] = ov;
  }
}

// -- main kernel: swapped QK^T (2-term f16 split), in-reg softmax, XCD-homed --
// 2-term: S = kh*qh + kh*ql (K residual dropped). Error enters only where
// sech^2(S/8) is large, i.e. where p=e^{10tanh-10} is negligible -> output
// absmax stays well under tolerance. QK MFMA 24->16, staging 6->4, LDS -33%.
__global__ __launch_bounds__(256, 4) void attn_mfma11(
    const float* __restrict__ Qg,
    const u16* __restrict__ Khi, const u16* __restrict__ VThi,
    const int* __restrict__ cnt, float* __restrict__ Og)
{
  // XCD-homing swizzle: all 16 qtile-blocks of a bh on ONE XCD; per-XCD K/V
  // set = 8 bh * 256 KB = 2 MB < 4 MB L2. Q via NT loads (no K/V eviction).
  const int blk = blockIdx.x;
  const int xcd = blk & 7, slot = blk >> 3;
  const int bh = ((slot >> 4) << 3) | xcd;   // 8 bh per XCD
  const int qtile = slot & 15;               // 0..15 (128 q-rows each)
  const int b = bh >> 3;
  const int tid = threadIdx.x, w = tid >> 6, lane = tid & 63;
  const int l32 = lane & 31, hl = lane >> 5;
  const int cntb = cnt[b];
  const int nt = (cntb + 63) >> 6;
  const bool partial = (cntb & 63) != 0;

  __shared__ short sKh[64 * PSTR];
  __shared__ short sVh[64 * PSTR];

  // ---- Q fragments (f16 hi/lo): lane holds Q[q=w*32+l32][k=s*16+hl*8+j] ----
  half8 qfh[4], qfl[4];
  {
    const float* qp = Qg + ((size_t)bh * N_ + qtile * 128 + w * 32 + l32) * D_ + hl * 8;
#pragma unroll
    for (int s = 0; s < 4; ++s) {
      f32x4 a = __builtin_nontemporal_load((const f32x4*)(qp + s * 16));
      f32x4 c = __builtin_nontemporal_load((const f32x4*)(qp + s * 16 + 4));
#pragma unroll
      for (int j = 0; j < 4; ++j) {
        _Float16 h0 = (_Float16)a[j];
        qfh[s][j] = h0; qfl[s][j] = (_Float16)(a[j] - (float)h0);
        _Float16 h1 = (_Float16)c[j];
        qfh[s][j + 4] = h1; qfl[s][j + 4] = (_Float16)(c[j] - (float)h1);
      }
    }
  }

  f32x16 accO0, accO1;
#pragma unroll
  for (int i = 0; i < 16; ++i) { accO0[i] = 0.f; accO1[i] = 0.f; }
  float dsum = 0.f;

  const size_t kvb = (size_t)bh * N_ * D_;

  // ---- prologue: prefetch tile 0 into registers ----
  short8 rKh[2], rVh[2];
#pragma unroll
  for (int cc = 0; cc < 2; ++cc) {
    const int ci = tid + cc * 256, row = ci >> 3, seg = ci & 7;
    rKh[cc] = *(const short8*)&Khi[kvb + (size_t)row * D_ + seg * 8];
    rVh[cc] = *(const short8*)&VThi[kvb + (size_t)row * N_ + seg * 8];
  }

  for (int kt = 0; kt < nt; ++kt) {
    __syncthreads();   // (A) prev tile's sK/sV reads complete

    // ---- staging: write prefetched regs to LDS (b128 ds_writes) ----
#pragma unroll
    for (int cc = 0; cc < 2; ++cc) {
      const int ci = tid + cc * 256, row = ci >> 3, seg = ci & 7;
      const int lofs = row * PSTR + seg * 8;
      *(short8*)&sKh[lofs] = rKh[cc];
      *(short8*)&sVh[lofs] = rVh[cc];
    }
    __syncthreads();   // (B)

    // ---- S^T = K Q^T: C col = q-row (l32), C rows = keys (in-register) ----
    f32x16 S0, S1;
#pragma unroll
    for (int i = 0; i < 16; ++i) { S0[i] = 0.f; S1[i] = 0.f; }
    __builtin_amdgcn_s_setprio(1);
#pragma unroll
    for (int s = 0; s < 4; ++s) {
      const int o0 = l32 * PSTR + s * 16 + hl * 8;
      half8 kfh = *(const half8*)&sKh[o0];
      S0 = __builtin_amdgcn_mfma_f32_32x32x16_f16(kfh, qfh[s], S0, 0, 0, 0);
      S0 = __builtin_amdgcn_mfma_f32_32x32x16_f16(kfh, qfl[s], S0, 0, 0, 0);
      const int o1 = (32 + l32) * PSTR + s * 16 + hl * 8;
      half8 kgh = *(const half8*)&sKh[o1];
      S1 = __builtin_amdgcn_mfma_f32_32x32x16_f16(kgh, qfh[s], S1, 0, 0, 0);
      S1 = __builtin_amdgcn_mfma_f32_32x32x16_f16(kgh, qfl[s], S1, 0, 0, 0);
    }
    __builtin_amdgcn_s_setprio(0);

    // ---- in-register softmax + pack + scalar denominator ----
    FragSum fs0, fs1, fs2, fs3;
    if (partial && kt == nt - 1) {
      const int rem = cntb - kt * 64 - 4 * hl;
      fs0 = pack8<true>(S0, 0, 0, rem);
      fs1 = pack8<true>(S0, 8, 0, rem);
      fs2 = pack8<true>(S1, 0, 32, rem);
      fs3 = pack8<true>(S1, 8, 32, rem);
    } else {
      fs0 = pack8<false>(S0, 0, 0, 0);
      fs1 = pack8<false>(S0, 8, 0, 0);
      fs2 = pack8<false>(S1, 0, 32, 0);
      fs3 = pack8<false>(S1, 8, 32, 0);
    }
    dsum += (fs0.s + fs1.s) + (fs2.s + fs3.s);

    // ---- prefetch next tile (clamped recompute; S0/S1 dead -> fits budget) ----
    {
      const int k0n = (kt + 1 < nt ? kt + 1 : kt) * 64;
#pragma unroll
      for (int cc = 0; cc < 2; ++cc) {
        const int ci = tid + cc * 256, row = ci >> 3, seg = ci & 7;
        rKh[cc] = *(const short8*)&Khi[kvb + (size_t)(k0n + row) * D_ + seg * 8];
        rVh[cc] = *(const short8*)&VThi[kvb + (size_t)row * N_ + k0n + seg * 8];
      }
    }

    // ---- O += P V (both d-halves) ----
    __builtin_amdgcn_s_setprio(1);
#define PV_STEP(sI, PF)                                                        \
    {                                                                          \
      const int o0 = l32 * PSTR + (sI) * 16 + hl * 8;                          \
      half8 v0 = *(const half8*)&sVh[o0];                                      \
      accO0 = __builtin_amdgcn_mfma_f32_32x32x16_f16((PF), v0, accO0, 0, 0, 0);\
      const int o1 = (32 + l32) * PSTR + (sI) * 16 + hl * 8;                   \
      half8 v1 = *(const half8*)&sVh[o1];                                      \
      accO1 = __builtin_amdgcn_mfma_f32_32x32x16_f16((PF), v1, accO1, 0, 0, 0);\
    }
    PV_STEP(0, fs0.f)
    PV_STEP(1, fs1.f)
    PV_STEP(2, fs2.f)
    PV_STEP(3, fs3.f)
#undef PV_STEP
    __builtin_amdgcn_s_setprio(0);
  }

  // ---- normalize and store (normal stores: L2 write-combining) ----
  float dtot = dsum + __shfl_xor(dsum, 32);
  const size_t obase = (size_t)bh * N_ + qtile * 128 + w * 32;
#pragma unroll
  for (int r = 0; r < 16; ++r) {
    const int row = (r & 3) + 8 * (r >> 2) + 4 * hl;
    float den = __shfl(dtot, row);   // lane 'row' holds q=row's denominator
    float inv = (den > 0.f) ? (1.f / den) : 0.f;
    Og[(obase + row) * D_ + l32]      = accO0[r] * inv;
    Og[(obase + row) * D_ + 32 + l32] = accO1[r] * inv;
  }
}

// --------------- fallback (R9, proven): in-kernel conversions ---------------
__global__ __launch_bounds__(256, 3) void attn_mfma(
    const float* __restrict__ Qg, const float* __restrict__ Kg,
    const float* __restrict__ Vg, const int* __restrict__ maskg,
    float* __restrict__ Og)
{
  const int qtile = blockIdx.x;
  const int bh    = blockIdx.y;
  const int b     = bh >> 3;
  const int tid   = threadIdx.x;
  const int w     = tid >> 6;
  const int lane  = tid & 63;
  const int l32   = lane & 31;
  const int hl    = lane >> 5;
  const int qh    = w >> 1;
  const int kh    = w & 1;

  __shared__ short sKh[64 * PSTR], sKl[64 * PSTR];
  __shared__ short sVh[64 * PSTR], sVl[64 * PSTR];
  __shared__ short sP [64 * PSTR];
  __shared__ float sM[64];

  short8 qfh[4], qfl[4];
  {
    const float* qp = Qg + ((size_t)bh * N_ + qtile * 64 + qh * 32 + l32) * D_ + hl * 8;
#pragma unroll
    for (int s = 0; s < 4; ++s) {
      f32x4 a = *(const f32x4*)(qp + s * 16);
      f32x4 c = *(const f32x4*)(qp + s * 16 + 4);
#pragma unroll
      for (int j = 0; j < 4; ++j) {
        u16 h0 = bfhi(a[j]);
        qfh[s][j] = (short)h0;
        qfl[s][j] = (short)bfhi(a[j] - bf2f(h0));
        u16 h1 = bfhi(c[j]);
        qfh[s][j + 4] = (short)h1;
        qfl[s][j + 4] = (short)bfhi(c[j] - bf2f(h1));
      }
    }
  }
  short8 ones;
#pragma unroll
  for (int j = 0; j < 8; ++j) ones[j] = (short)((l32 == 0) ? 0x3F80 : 0);
  f32x16 accO, accD;
#pragma unroll
  for (int i = 0; i < 16; ++i) { accO[i] = 0.f; accD[i] = 0.f; }
  const size_t kvbase = (size_t)bh * N_ * D_;

  for (int kt = 0; kt < N_ / 64; ++kt) {
    const int k0 = kt * 64;
    __syncthreads();
    {
      const int row = tid >> 2, seg = tid & 3;
      const float* kp = Kg + kvbase + (size_t)(k0 + row) * D_ + seg * 16;
      short8 h0, h1, l0, l1;
#pragma unroll
      for (int i2 = 0; i2 < 2; ++i2) {
        f32x4 t0 = *(const f32x4*)(kp + i2 * 8);
        f32x4 t1 = *(const f32x4*)(kp + i2 * 8 + 4);
#pragma unroll
        for (int j = 0; j < 4; ++j) {
          u16 ha = bfhi(t0[j]); u16 la = bfhi(t0[j] - bf2f(ha));
          u16 hb = bfhi(t1[j]); u16 lb = bfhi(t1[j] - bf2f(hb));
          if (i2 == 0) { h0[j]=(short)ha; l0[j]=(short)la; h0[j+4]=(short)hb; l0[j+4]=(short)lb; }
          else         { h1[j]=(short)ha; l1[j]=(short)la; h1[j+4]=(short)hb; l1[j+4]=(short)lb; }
        }
      }
      *(short8*)&sKh[row * PSTR + seg * 16]     = h0;
      *(short8*)&sKh[row * PSTR + seg * 16 + 8] = h1;
      *(short8*)&sKl[row * PSTR + seg * 16]     = l0;
      *(short8*)&sKl[row * PSTR + seg * 16 + 8] = l1;
    }
    {
      const float* vp = Vg + kvbase + (size_t)(k0 + w * 16) * D_ + lane;
      float vv[16];
#pragma unroll
      for (int kk = 0; kk < 16; ++kk) vv[kk] = vp[(size_t)kk * D_];
      short8 h0, h1, l0, l1;
#pragma unroll
      for (int kk = 0; kk < 8; ++kk) {
        u16 ha = bfhi(vv[kk]);     h0[kk]=(short)ha; l0[kk]=(short)bfhi(vv[kk]-bf2f(ha));
        u16 hb = bfhi(vv[kk + 8]); h1[kk]=(short)hb; l1[kk]=(short)bfhi(vv[kk+8]-bf2f(hb));
      }
      *(short8*)&sVh[lane * PSTR + w * 16]     = h0;
      *(short8*)&sVh[lane * PSTR + w * 16 + 8] = h1;
      *(short8*)&sVl[lane * PSTR + w * 16]     = l0;
      *(short8*)&sVl[lane * PSTR + w * 16 + 8] = l1;
    }
    if (tid < 64) sM[tid] = maskg[b * N_ + k0 + tid] ? 0.f : 1.f;
    __syncthreads();

    f32x16 S;
#pragma unroll
    for (int i = 0; i < 16; ++i) S[i] = 0.f;
#pragma unroll
    for (int s = 0; s < 4; ++s) {
      const int off = (kh * 32 + l32) * PSTR + s * 16 + hl * 8;
      short8 kfh = *(const short8*)&sKh[off];
      short8 kfl = *(const short8*)&sKl[off];
      S = __builtin_amdgcn_mfma_f32_32x32x16_bf16(qfh[s], kfh, S, 0, 0, 0);
      S = __builtin_amdgcn_mfma_f32_32x32x16_bf16(qfl[s], kfh, S, 0, 0, 0);
      S = __builtin_amdgcn_mfma_f32_32x32x16_bf16(qfh[s], kfl, S, 0, 0, 0);
    }
    const float pm = sM[kh * 32 + l32];
#pragma unroll
    for (int r = 0; r < 16; ++r) {
      float x  = S[r] * 0.125f;
      float ax = fminf(fabsf(x), 30.f);
      float z  = __builtin_amdgcn_exp2f(ax * -2.8853900817779268f);
      float nu = (x >= 0.f) ? z : 1.f;
      float e  = nu * __builtin_amdgcn_rcpf(1.f + z) * -28.853900817779268f;
      float p  = __builtin_amdgcn_exp2f(e) * pm;
      const int row = qh * 32 + (r & 3) + 8 * (r >> 2) + 4 * hl;
      sP[row * PSTR + kh * 32 + l32] = (short)bfhi(p);
    }
    __syncthreads();
#pragma unroll
    for (int s = 0; s < 4; ++s) {
      short8 pf  = *(const short8*)&sP[(qh * 32 + l32) * PSTR + s * 16 + hl * 8];
      const int voff = (kh * 32 + l32) * PSTR + s * 16 + hl * 8;
      short8 vfh = *(const short8*)&sVh[voff];
      short8 vfl = *(const short8*)&sVl[voff];
      accO = __builtin_amdgcn_mfma_f32_32x32x16_bf16(pf, vfh, accO, 0, 0, 0);
      accO = __builtin_amdgcn_mfma_f32_32x32x16_bf16(pf, vfl, accO, 0, 0, 0);
      accD = __builtin_amdgcn_mfma_f32_32x32x16_bf16(pf, ones, accD, 0, 0, 0);
    }
  }
  const size_t obase = (size_t)bh * N_ + qtile * 64 + qh * 32;
#pragma unroll
  for (int r = 0; r < 16; ++r) {
    float den = __shfl(accD[r], lane & 32);
    float inv = (den > 0.f) ? (1.f / den) : 0.f;
    const int row = (r & 3) + 8 * (r >> 2) + 4 * hl;
    Og[(obase + row) * D_ + kh * 32 + l32] = accO[r] * inv;
  }
}

extern "C" void kernel_launch(void* const* d_in, const int* in_sizes, int n_in,
                              void* d_out, int out_size, void* d_ws, size_t ws_size,
                              hipStream_t stream) {
  const float* Q = (const float*)d_in[0];
  const float* K = (const float*)d_in[1];
  const float* V = (const float*)d_in[2];
  const int* mask = (const int*)d_in[3];
  float* out = (float*)d_out;
  dim3 block(256);
  if (ws_size >= (size_t)WS_NEED) {
    u16* wsp  = (u16*)d_ws;
    u16* Khi  = wsp;
    u16* VThi = wsp + ELEMS;
    int* cntp = (int*)(wsp + 2 * (size_t)ELEMS);
    conv_kv4<<<dim3(32, 64), block, 0, stream>>>(K, V, mask, Khi, VThi, cntp);
    attn_mfma11<<<dim3(1024), block, 0, stream>>>(Q, Khi, VThi, cntp, out);
  } else {
    attn_mfma<<<dim3(32, 64), block, 0, stream>>>(Q, K, V, mask, out);
  }
}